// Round 1
// baseline (1074.562 us; speedup 1.0000x reference)
//
#include <hip/hip_runtime.h>
#include <hip/hip_bf16.h>
#include <cstdint>
#include <cstddef>

// Problem constants
#define B_   2
#define T_   2048
#define DIM_ 4096
#define H_   32
#define HKV_ 8
#define DH_  128
// M dimension of all GEMMs
#define MROWS (B_*T_)   // 4096

typedef __bf16 bf16_t;
typedef bf16_t bf16x8 __attribute__((ext_vector_type(8)));
typedef bf16_t bf16x4 __attribute__((ext_vector_type(4)));
typedef float  f32x4  __attribute__((ext_vector_type(4)));

typedef __attribute__((address_space(1))) void gvoid_t;
typedef __attribute__((address_space(3))) void lvoid_t;

__device__ __forceinline__ void gld_lds16(const void* g, void* l) {
  // async global->LDS, 16B per lane; LDS dest is wave-uniform base + lane*16
  __builtin_amdgcn_global_load_lds((gvoid_t*)g, (lvoid_t*)l, 16, 0, 0);
}

__device__ __forceinline__ f32x4 mfma16(bf16x8 a, bf16x8 b, f32x4 c) {
  return __builtin_amdgcn_mfma_f32_16x16x32_bf16(a, b, c, 0, 0, 0);
}

// ---------------------------------------------------------------------------
// 1) elementwise cast fp32 -> bf16 (X)
// ---------------------------------------------------------------------------
__global__ void cast_f32_bf16(const float* __restrict__ in,
                              bf16_t* __restrict__ out, int n4) {
  int i = blockIdx.x * blockDim.x + threadIdx.x;
  if (i < n4) {
    float4 v = ((const float4*)in)[i];
    bf16x4 o;
    o[0] = (bf16_t)v.x; o[1] = (bf16_t)v.y; o[2] = (bf16_t)v.z; o[3] = (bf16_t)v.w;
    ((bf16x4*)out)[i] = o;
  }
}

// ---------------------------------------------------------------------------
// 2) transpose + cast: in fp32 [K][N] -> out bf16 [N][K]
// ---------------------------------------------------------------------------
__global__ void transpose_cast(const float* __restrict__ in,
                               bf16_t* __restrict__ out, int K, int N) {
  __shared__ float tile[32][33];
  int n0 = blockIdx.x * 32, k0 = blockIdx.y * 32;
  int tx = threadIdx.x, ty = threadIdx.y;
#pragma unroll
  for (int j = 0; j < 4; ++j)
    tile[ty + j*8][tx] = in[(size_t)(k0 + ty + j*8) * N + n0 + tx];
  __syncthreads();
#pragma unroll
  for (int j = 0; j < 4; ++j)
    out[(size_t)(n0 + ty + j*8) * K + k0 + tx] = (bf16_t)tile[tx][ty + j*8];
}

// ---------------------------------------------------------------------------
// 3) bf16 MFMA GEMM, m97 structure: C[M][N] = A[M][K] * BT[N][K]^T
//    128x128 tile, BK=32, 256 threads (2x2 waves, 4x4 16x16 frags each)
// ---------------------------------------------------------------------------
template <int OUT_F32>
__global__ __launch_bounds__(256, 2)
void gemm_bt(const bf16_t* __restrict__ A, const bf16_t* __restrict__ BT,
             void* __restrict__ C, int M, int N, int K) {
  __shared__ __align__(16) bf16_t Als[128 * 32];
  __shared__ __align__(16) bf16_t Bls[128 * 32];
  const int tid  = threadIdx.x;
  const int wave = tid >> 6, lane = tid & 63;
  const int quad = lane >> 4, l16 = lane & 15;
  const int wm = wave >> 1, wn = wave & 1;
  const int m0 = blockIdx.y * 128, n0 = blockIdx.x * 128;

  f32x4 acc[4][4] = {};

  const int srow = lane >> 2;        // 0..15 within 1KB chunk (16 rows x 64B)
  const int scol = (lane & 3) * 8;   // element offset

  for (int k0 = 0; k0 < K; k0 += 32) {
    // stage A tile [128][32] : 8 chunks of 1KB, 2 per wave
#pragma unroll
    for (int c = 0; c < 2; ++c) {
      int ch = wave * 2 + c;
      gld_lds16(A + (size_t)(m0 + ch*16 + srow) * K + k0 + scol,
                &Als[ch*512 + srow*32 + scol]);
    }
    // stage BT tile [128][32]
#pragma unroll
    for (int c = 0; c < 2; ++c) {
      int ch = wave * 2 + c;
      gld_lds16(BT + (size_t)(n0 + ch*16 + srow) * K + k0 + scol,
                &Bls[ch*512 + srow*32 + scol]);
    }
    __syncthreads();

    bf16x8 af[4], bfr[4];
#pragma unroll
    for (int mi = 0; mi < 4; ++mi)
      af[mi] = *(const bf16x8*)&Als[(wm*64 + mi*16 + l16)*32 + quad*8];
#pragma unroll
    for (int ni = 0; ni < 4; ++ni)
      bfr[ni] = *(const bf16x8*)&Bls[(wn*64 + ni*16 + l16)*32 + quad*8];
#pragma unroll
    for (int mi = 0; mi < 4; ++mi)
#pragma unroll
      for (int ni = 0; ni < 4; ++ni)
        acc[mi][ni] = mfma16(af[mi], bfr[ni], acc[mi][ni]);
    __syncthreads();
  }

  // epilogue: C/D layout col = lane&15, row = quad*4 + r
#pragma unroll
  for (int mi = 0; mi < 4; ++mi)
#pragma unroll
    for (int ni = 0; ni < 4; ++ni)
#pragma unroll
      for (int r = 0; r < 4; ++r) {
        int row = m0 + wm*64 + mi*16 + quad*4 + r;
        int col = n0 + wn*64 + ni*16 + l16;
        if (OUT_F32)
          ((float*)C)[(size_t)row * N + col] = acc[mi][ni][r];
        else
          ((bf16_t*)C)[(size_t)row * N + col] = (bf16_t)acc[mi][ni][r];
      }
}

// ---------------------------------------------------------------------------
// 4) in-place RoPE on bf16 [B,T,Hn,128]; pairs (d, d+64), pos = t
// ---------------------------------------------------------------------------
__global__ void rope_kernel(bf16_t* __restrict__ X, int Hn, int total) {
  int i = blockIdx.x * blockDim.x + threadIdx.x;
  if (i >= total) return;
  int d   = i & 63;
  int rem = i >> 6;
  int h   = rem % Hn; rem /= Hn;
  int t   = rem % T_;
  int b   = rem / T_;
  size_t base = ((size_t)(b * T_ + t) * Hn + h) * DH_;
  float x1 = (float)X[base + d];
  float x2 = (float)X[base + 64 + d];
  // inv_freq = theta^(-d/64) = exp(-d * ln(10000)/64)
  float inv_freq = expf(-(float)d * 0.14391156758f);
  float ang = (float)t * inv_freq;
  float s, c;
  sincosf(ang, &s, &c);
  X[base + d]      = (bf16_t)(x1 * c - x2 * s);
  X[base + 64 + d] = (bf16_t)(x1 * s + x2 * c);
}

// ---------------------------------------------------------------------------
// 5) V transpose: Vb [b][t][kv][128] -> VT [b][kv][128][T]
// ---------------------------------------------------------------------------
__global__ void v_transpose(const bf16_t* __restrict__ Vb,
                            bf16_t* __restrict__ VT) {
  __shared__ bf16_t tile[32][33];
  int t0 = blockIdx.x * 32;   // T
  int d0 = blockIdx.y * 32;   // dh
  int bk = blockIdx.z;        // b*8+kv
  int b = bk >> 3, kv = bk & 7;
  int tx = threadIdx.x, ty = threadIdx.y;
#pragma unroll
  for (int j = 0; j < 4; ++j)
    tile[ty + j*8][tx] =
        Vb[(size_t)(b * T_ + t0 + ty + j*8) * (HKV_*DH_) + kv*DH_ + d0 + tx];
  __syncthreads();
#pragma unroll
  for (int j = 0; j < 4; ++j)
    VT[((size_t)bk * DH_ + d0 + ty + j*8) * T_ + t0 + tx] = tile[tx][ty + j*8];
}

// ---------------------------------------------------------------------------
// 6) causal flash attention, BQ=128, BKV=64, 256 threads
//    grid (T/128, H, B). kv head = h>>2 (G=4).
//
//    Round-1 restructure:
//      - LPT: qt = gridDim.x-1-blockIdx.x (longest blocks dispatch first)
//      - double-buffered K/V with stage-ahead: next tile's global_load_lds
//        issued right after the loop-top barrier; drained by the NEXT
//        loop-top __syncthreads (vmcnt0) -> staging hidden under compute
//      - PV reads only the wave's OWN P rows -> P-write/PV barrier removed;
//        single __syncthreads per kv-tile (was 3)
//      - P stored XOR-swizzled [128][64] (16B granule ^ row&7), 16 KB
//      - softmax in raw-score domain: p = exp2(fma(s, S2, -m*S2)),
//        S2 = (1/sqrt(128))*log2(e); mask value -1e30 keeps exp2 finite
//      - defer-max (T13): skip o_acc rescale when __all(mx <= m + 8/sc)
//      - s_setprio(1) around both MFMA clusters (T5)
//    LDS: 2*16K (K) + 2*16K (V) + 16K (P) = 80 KB -> 2 blocks/CU
// ---------------------------------------------------------------------------
__global__ __launch_bounds__(256, 2)
void flash_attn(const bf16_t* __restrict__ Qb, const bf16_t* __restrict__ Kb,
                const bf16_t* __restrict__ VT, bf16_t* __restrict__ Ob) {
  __shared__ __align__(16) bf16_t Kls[2][64 * 128];   // [kv][dh], 16B-granule swizzle by row&7
  __shared__ __align__(16) bf16_t Vls[2][128 * 64];   // [dh][kv], swizzle by row&7
  __shared__ __align__(16) bf16_t Pls[128 * 64];      // [q][kv], swizzle by row&7

  const int tid = threadIdx.x, wave = tid >> 6, lane = tid & 63;
  const int quad = lane >> 4, l16 = lane & 15;
  const int qt = (int)gridDim.x - 1 - (int)blockIdx.x;   // LPT remap
  const int h = blockIdx.y, b = blockIdx.z;
  const int kv = h >> 2;

  // Q fragments (rope already applied): rows wave*32 + mi*16 + l16
  bf16x8 q[2][4];
#pragma unroll
  for (int mi = 0; mi < 2; ++mi) {
    const bf16_t* base =
        Qb + (size_t)(b*T_ + qt*128 + wave*32 + mi*16 + l16) * DIM_ + h*DH_;
#pragma unroll
    for (int kk = 0; kk < 4; ++kk)
      q[mi][kk] = *(const bf16x8*)(base + kk*32 + quad*8);
  }

  float m_st[2][4], l_st[2][4];
  f32x4 o_acc[2][8] = {};
#pragma unroll
  for (int mi = 0; mi < 2; ++mi)
#pragma unroll
    for (int r = 0; r < 4; ++r) { m_st[mi][r] = -1e30f; l_st[mi][r] = 0.f; }

  const int nkv = 2 * (qt + 1);

  // async stage of K/V tile kvt into buffer parity pb
  auto stage = [&](int kvt, int pb) {
    int r_in = lane >> 4, cph = lane & 15;
#pragma unroll
    for (int c = 0; c < 4; ++c) {
      int ch = wave * 4 + c;
      int krow = ch * 4 + r_in;
      int clog = cph ^ (krow & 7);
      gld_lds16(Kb + (size_t)(b*T_ + kvt*64 + krow) * (HKV_*DH_) + kv*DH_ + clog*8,
                &Kls[pb][ch*512 + lane*8]);
    }
    int r8 = lane >> 3, c8 = lane & 7;
#pragma unroll
    for (int c = 0; c < 4; ++c) {
      int ch = wave * 4 + c;
      int drow = ch * 8 + r8;
      int clog = c8 ^ (drow & 7);
      gld_lds16(VT + ((size_t)(b*HKV_ + kv) * DH_ + drow) * T_ + kvt*64 + clog*8,
                &Vls[pb][ch*512 + lane*8]);
    }
  };

  stage(0, 0);

  const float S2 = 0.08838834764831845f * 1.4426950408889634f; // sc*log2(e)
  const float THRraw = 8.0f / 0.08838834764831845f;            // defer threshold (raw)

  for (int kvt = 0; kvt < nkv; ++kvt) {
    const int p = kvt & 1;
    __syncthreads();   // drains own stage(kvt) loads (vmcnt0) + all waves done with buf p^1
    if (kvt + 1 < nkv) stage(kvt + 1, p ^ 1);

    // S = Q K^T (per wave: rows wave*32..+32, cols 0..64)
    f32x4 s[2][4] = {};
    __builtin_amdgcn_s_setprio(1);
#pragma unroll
    for (int kk = 0; kk < 4; ++kk) {
      bf16x8 kf[4];
#pragma unroll
      for (int ni = 0; ni < 4; ++ni) {
        int krow = ni*16 + l16;
        int cphys = (kk*4 + quad) ^ (krow & 7);
        kf[ni] = *(const bf16x8*)&Kls[p][krow*128 + cphys*8];
      }
#pragma unroll
      for (int mi = 0; mi < 2; ++mi)
#pragma unroll
        for (int ni = 0; ni < 4; ++ni)
          s[mi][ni] = mfma16(q[mi][kk], kf[ni], s[mi][ni]);
    }
    __builtin_amdgcn_s_setprio(0);

    // causal mask + online softmax (raw-score domain)
    const bool need_mask = (kvt >= 2*qt);
#pragma unroll
    for (int mi = 0; mi < 2; ++mi) {
      float mx[4];
#pragma unroll
      for (int r = 0; r < 4; ++r) {
        int rpos = qt*128 + wave*32 + mi*16 + quad*4 + r;
        float m = -1e30f;
#pragma unroll
        for (int ni = 0; ni < 4; ++ni) {
          float v = s[mi][ni][r];
          if (need_mask) {
            int cpos = kvt*64 + ni*16 + l16;
            if (cpos > rpos) v = -1e30f;
          }
          s[mi][ni][r] = v;
          m = fmaxf(m, v);
        }
#pragma unroll
        for (int off = 1; off < 16; off <<= 1)
          m = fmaxf(m, __shfl_xor(m, off, 64));
        mx[r] = m;
      }
      // defer-max vote (wave-uniform branch)
      bool defer = true;
#pragma unroll
      for (int r = 0; r < 4; ++r)
        defer = defer && (mx[r] <= m_st[mi][r] + THRraw);
      if (__all(defer)) {
#pragma unroll
        for (int r = 0; r < 4; ++r) {
          float mn2 = m_st[mi][r] * S2;
          float rs = 0.f;
#pragma unroll
          for (int ni = 0; ni < 4; ++ni) {
            float pv = __builtin_amdgcn_exp2f(fmaf(s[mi][ni][r], S2, -mn2));
            s[mi][ni][r] = pv;
            rs += pv;
          }
#pragma unroll
          for (int off = 1; off < 16; off <<= 1)
            rs += __shfl_xor(rs, off, 64);
          l_st[mi][r] += rs;
        }
      } else {
        float al[4];
#pragma unroll
        for (int r = 0; r < 4; ++r) {
          float mnew = fmaxf(m_st[mi][r], mx[r]);
          al[r] = __builtin_amdgcn_exp2f((m_st[mi][r] - mnew) * S2);
          m_st[mi][r] = mnew;
          float mn2 = mnew * S2;
          float rs = 0.f;
#pragma unroll
          for (int ni = 0; ni < 4; ++ni) {
            float pv = __builtin_amdgcn_exp2f(fmaf(s[mi][ni][r], S2, -mn2));
            s[mi][ni][r] = pv;
            rs += pv;
          }
#pragma unroll
          for (int off = 1; off < 16; off <<= 1)
            rs += __shfl_xor(rs, off, 64);
          l_st[mi][r] = l_st[mi][r] * al[r] + rs;
        }
#pragma unroll
        for (int ni = 0; ni < 8; ++ni)
#pragma unroll
          for (int r = 0; r < 4; ++r) o_acc[mi][ni][r] *= al[r];
      }
      // P -> LDS, swizzled [128][64]; rows are wave-private
#pragma unroll
      for (int ni = 0; ni < 4; ++ni)
#pragma unroll
        for (int r = 0; r < 4; ++r) {
          int prow = wave*32 + mi*16 + quad*4 + r;
          int g = (ni*2 + (l16 >> 3)) ^ (prow & 7);
          Pls[prow*64 + g*8 + (l16 & 7)] = (bf16_t)s[mi][ni][r];
        }
    }

    // O += P V  (P rows are same-wave: ds_write->ds_read ordered by lgkmcnt,
    // no barrier needed). A = P[128][64], B^T = VT[128][64]
    __builtin_amdgcn_s_setprio(1);
#pragma unroll
    for (int kk = 0; kk < 2; ++kk) {
      bf16x8 pf[2], vf[8];
#pragma unroll
      for (int mi = 0; mi < 2; ++mi) {
        int prow = wave*32 + mi*16 + l16;
        int g = (kk*4 + quad) ^ (prow & 7);
        pf[mi] = *(const bf16x8*)&Pls[prow*64 + g*8];
      }
#pragma unroll
      for (int ni = 0; ni < 8; ++ni) {
        int drow = ni*16 + l16;
        int cphys = (kk*4 + quad) ^ (drow & 7);
        vf[ni] = *(const bf16x8*)&Vls[p][drow*64 + cphys*8];
      }
#pragma unroll
      for (int mi = 0; mi < 2; ++mi)
#pragma unroll
        for (int ni = 0; ni < 8; ++ni)
          o_acc[mi][ni] = mfma16(pf[mi], vf[ni], o_acc[mi][ni]);
    }
    __builtin_amdgcn_s_setprio(0);
  }

  // epilogue: normalize and store bf16
#pragma unroll
  for (int mi = 0; mi < 2; ++mi) {
    float inv[4];
#pragma unroll
    for (int r = 0; r < 4; ++r) inv[r] = 1.f / l_st[mi][r];
#pragma unroll
    for (int ni = 0; ni < 8; ++ni)
#pragma unroll
      for (int r = 0; r < 4; ++r) {
        size_t row = (size_t)(b*T_ + qt*128 + wave*32 + mi*16 + quad*4 + r);
        int col = h*DH_ + ni*16 + l16;
        Ob[row * DIM_ + col] = (bf16_t)(o_acc[mi][ni][r] * inv[r]);
      }
  }
}

// ---------------------------------------------------------------------------
// launch
// ---------------------------------------------------------------------------
extern "C" void kernel_launch(void* const* d_in, const int* in_sizes, int n_in,
                              void* d_out, int out_size, void* d_ws, size_t ws_size,
                              hipStream_t stream) {
  const float* X  = (const float*)d_in[0];
  const float* Wq = (const float*)d_in[1];
  const float* Wk = (const float*)d_in[2];
  const float* Wv = (const float*)d_in[3];
  const float* Wo = (const float*)d_in[4];
  float* out = (float*)d_out;

  // workspace layout (bytes); total ~176.2 MB
  char* ws = (char*)d_ws;
  const size_t SZ_X  = (size_t)MROWS * DIM_ * 2;   // 33.55 MB
  const size_t SZ_WQ = (size_t)DIM_ * DIM_ * 2;    // 33.55 MB
  const size_t SZ_WK = (size_t)DIM_ * 1024 * 2;    // 8.39 MB
  bf16_t* Xb  = (bf16_t*)(ws);                       // X bf16; reused as Ob
  bf16_t* WqT = (bf16_t*)(ws + SZ_X);
  bf16_t* WkT = (bf16_t*)(ws + SZ_X + SZ_WQ);
  bf16_t* WvT = (bf16_t*)(ws + SZ_X + SZ_WQ + SZ_WK);
  bf16_t* WoT = (bf16_t*)(ws + SZ_X + SZ_WQ + 2*SZ_WK);
  bf16_t* Qb  = (bf16_t*)(ws + SZ_X + 2*SZ_WQ + 2*SZ_WK);
  bf16_t* Kb  = (bf16_t*)(ws + 2*SZ_X + 2*SZ_WQ + 2*SZ_WK);
  bf16_t* Vb  = (bf16_t*)(ws + 2*SZ_X + 2*SZ_WQ + 3*SZ_WK);
  bf16_t* VT  = (bf16_t*)(ws + 2*SZ_X + 2*SZ_WQ + 4*SZ_WK);
  bf16_t* Ob  = Xb;  // X dead after QKV GEMMs

  // 1) casts / transposes
  {
    int n4 = MROWS * DIM_ / 4;
    cast_f32_bf16<<<(n4 + 255)/256, 256, 0, stream>>>(X, Xb, n4);
  }
  transpose_cast<<<dim3(DIM_/32, DIM_/32), dim3(32,8), 0, stream>>>(Wq, WqT, DIM_, DIM_);
  transpose_cast<<<dim3(1024/32, DIM_/32), dim3(32,8), 0, stream>>>(Wk, WkT, DIM_, 1024);
  transpose_cast<<<dim3(1024/32, DIM_/32), dim3(32,8), 0, stream>>>(Wv, WvT, DIM_, 1024);
  transpose_cast<<<dim3(DIM_/32, DIM_/32), dim3(32,8), 0, stream>>>(Wo, WoT, DIM_, DIM_);

  // 2) QKV projections
  gemm_bt<0><<<dim3(DIM_/128, MROWS/128), 256, 0, stream>>>(Xb, WqT, Qb, MROWS, DIM_, DIM_);
  gemm_bt<0><<<dim3(1024/128, MROWS/128), 256, 0, stream>>>(Xb, WkT, Kb, MROWS, 1024, DIM_);
  gemm_bt<0><<<dim3(1024/128, MROWS/128), 256, 0, stream>>>(Xb, WvT, Vb, MROWS, 1024, DIM_);

  // 3) RoPE (in place)
  {
    int totq = B_ * T_ * H_ * 64;
    rope_kernel<<<(totq + 255)/256, 256, 0, stream>>>(Qb, H_, totq);
    int totk = B_ * T_ * HKV_ * 64;
    rope_kernel<<<(totk + 255)/256, 256, 0, stream>>>(Kb, HKV_, totk);
  }

  // 4) V transpose
  v_transpose<<<dim3(T_/32, DH_/32, B_*HKV_), dim3(32,8), 0, stream>>>(Vb, VT);

  // 5) flash attention
  flash_attn<<<dim3(T_/128, H_, B_), 256, 0, stream>>>(Qb, Kb, VT, Ob);

  // 6) output projection -> fp32 d_out
  gemm_bt<1><<<dim3(DIM_/128, MROWS/128), 256, 0, stream>>>(Ob, WoT, out, MROWS, DIM_, DIM_);
}

// Round 2
// 989.346 us; speedup vs baseline: 1.0861x; 1.0861x over previous
//
#include <hip/hip_runtime.h>
#include <hip/hip_bf16.h>
#include <cstdint>
#include <cstddef>

// Problem constants
#define B_   2
#define T_   2048
#define DIM_ 4096
#define H_   32
#define HKV_ 8
#define DH_  128
// M dimension of all GEMMs
#define MROWS (B_*T_)   // 4096

typedef __bf16 bf16_t;
typedef bf16_t bf16x8 __attribute__((ext_vector_type(8)));
typedef bf16_t bf16x4 __attribute__((ext_vector_type(4)));
typedef float  f32x4  __attribute__((ext_vector_type(4)));

typedef __attribute__((address_space(1))) void gvoid_t;
typedef __attribute__((address_space(3))) void lvoid_t;

__device__ __forceinline__ void gld_lds16(const void* g, void* l) {
  // async global->LDS, 16B per lane; LDS dest is wave-uniform base + lane*16
  __builtin_amdgcn_global_load_lds((gvoid_t*)g, (lvoid_t*)l, 16, 0, 0);
}

__device__ __forceinline__ f32x4 mfma16(bf16x8 a, bf16x8 b, f32x4 c) {
  return __builtin_amdgcn_mfma_f32_16x16x32_bf16(a, b, c, 0, 0, 0);
}

// ---------------------------------------------------------------------------
// 1) elementwise cast fp32 -> bf16 (X)
// ---------------------------------------------------------------------------
__global__ void cast_f32_bf16(const float* __restrict__ in,
                              bf16_t* __restrict__ out, int n4) {
  int i = blockIdx.x * blockDim.x + threadIdx.x;
  if (i < n4) {
    float4 v = ((const float4*)in)[i];
    bf16x4 o;
    o[0] = (bf16_t)v.x; o[1] = (bf16_t)v.y; o[2] = (bf16_t)v.z; o[3] = (bf16_t)v.w;
    ((bf16x4*)out)[i] = o;
  }
}

// ---------------------------------------------------------------------------
// 2) transpose + cast: in fp32 [K][N] -> out bf16 [N][K]
// ---------------------------------------------------------------------------
__global__ void transpose_cast(const float* __restrict__ in,
                               bf16_t* __restrict__ out, int K, int N) {
  __shared__ float tile[32][33];
  int n0 = blockIdx.x * 32, k0 = blockIdx.y * 32;
  int tx = threadIdx.x, ty = threadIdx.y;
#pragma unroll
  for (int j = 0; j < 4; ++j)
    tile[ty + j*8][tx] = in[(size_t)(k0 + ty + j*8) * N + n0 + tx];
  __syncthreads();
#pragma unroll
  for (int j = 0; j < 4; ++j)
    out[(size_t)(n0 + ty + j*8) * K + k0 + tx] = (bf16_t)tile[tx][ty + j*8];
}

// ---------------------------------------------------------------------------
// 3) bf16 MFMA GEMM, m97 structure: C[M][N] = A[M][K] * BT[N][K]^T
//    128x128 tile, BK=32, 256 threads (2x2 waves, 4x4 16x16 frags each)
// ---------------------------------------------------------------------------
template <int OUT_F32>
__global__ __launch_bounds__(256, 2)
void gemm_bt(const bf16_t* __restrict__ A, const bf16_t* __restrict__ BT,
             void* __restrict__ C, int M, int N, int K) {
  __shared__ __align__(16) bf16_t Als[128 * 32];
  __shared__ __align__(16) bf16_t Bls[128 * 32];
  const int tid  = threadIdx.x;
  const int wave = tid >> 6, lane = tid & 63;
  const int quad = lane >> 4, l16 = lane & 15;
  const int wm = wave >> 1, wn = wave & 1;
  const int m0 = blockIdx.y * 128, n0 = blockIdx.x * 128;

  f32x4 acc[4][4] = {};

  const int srow = lane >> 2;        // 0..15 within 1KB chunk (16 rows x 64B)
  const int scol = (lane & 3) * 8;   // element offset

  for (int k0 = 0; k0 < K; k0 += 32) {
    // stage A tile [128][32] : 8 chunks of 1KB, 2 per wave
#pragma unroll
    for (int c = 0; c < 2; ++c) {
      int ch = wave * 2 + c;
      gld_lds16(A + (size_t)(m0 + ch*16 + srow) * K + k0 + scol,
                &Als[ch*512 + srow*32 + scol]);
    }
    // stage BT tile [128][32]
#pragma unroll
    for (int c = 0; c < 2; ++c) {
      int ch = wave * 2 + c;
      gld_lds16(BT + (size_t)(n0 + ch*16 + srow) * K + k0 + scol,
                &Bls[ch*512 + srow*32 + scol]);
    }
    __syncthreads();

    bf16x8 af[4], bfr[4];
#pragma unroll
    for (int mi = 0; mi < 4; ++mi)
      af[mi] = *(const bf16x8*)&Als[(wm*64 + mi*16 + l16)*32 + quad*8];
#pragma unroll
    for (int ni = 0; ni < 4; ++ni)
      bfr[ni] = *(const bf16x8*)&Bls[(wn*64 + ni*16 + l16)*32 + quad*8];
#pragma unroll
    for (int mi = 0; mi < 4; ++mi)
#pragma unroll
      for (int ni = 0; ni < 4; ++ni)
        acc[mi][ni] = mfma16(af[mi], bfr[ni], acc[mi][ni]);
    __syncthreads();
  }

  // epilogue: C/D layout col = lane&15, row = quad*4 + r
#pragma unroll
  for (int mi = 0; mi < 4; ++mi)
#pragma unroll
    for (int ni = 0; ni < 4; ++ni)
#pragma unroll
      for (int r = 0; r < 4; ++r) {
        int row = m0 + wm*64 + mi*16 + quad*4 + r;
        int col = n0 + wn*64 + ni*16 + l16;
        if (OUT_F32)
          ((float*)C)[(size_t)row * N + col] = acc[mi][ni][r];
        else
          ((bf16_t*)C)[(size_t)row * N + col] = (bf16_t)acc[mi][ni][r];
      }
}

// ---------------------------------------------------------------------------
// 4) in-place RoPE on bf16 [B,T,Hn,128]; pairs (d, d+64), pos = t
// ---------------------------------------------------------------------------
__global__ void rope_kernel(bf16_t* __restrict__ X, int Hn, int total) {
  int i = blockIdx.x * blockDim.x + threadIdx.x;
  if (i >= total) return;
  int d   = i & 63;
  int rem = i >> 6;
  int h   = rem % Hn; rem /= Hn;
  int t   = rem % T_;
  int b   = rem / T_;
  size_t base = ((size_t)(b * T_ + t) * Hn + h) * DH_;
  float x1 = (float)X[base + d];
  float x2 = (float)X[base + 64 + d];
  // inv_freq = theta^(-d/64) = exp(-d * ln(10000)/64)
  float inv_freq = expf(-(float)d * 0.14391156758f);
  float ang = (float)t * inv_freq;
  float s, c;
  sincosf(ang, &s, &c);
  X[base + d]      = (bf16_t)(x1 * c - x2 * s);
  X[base + 64 + d] = (bf16_t)(x1 * s + x2 * c);
}

// ---------------------------------------------------------------------------
// 5) V transpose: Vb [b][t][kv][128] -> VT [b][kv][128][T]
// ---------------------------------------------------------------------------
__global__ void v_transpose(const bf16_t* __restrict__ Vb,
                            bf16_t* __restrict__ VT) {
  __shared__ bf16_t tile[32][33];
  int t0 = blockIdx.x * 32;   // T
  int d0 = blockIdx.y * 32;   // dh
  int bk = blockIdx.z;        // b*8+kv
  int b = bk >> 3, kv = bk & 7;
  int tx = threadIdx.x, ty = threadIdx.y;
#pragma unroll
  for (int j = 0; j < 4; ++j)
    tile[ty + j*8][tx] =
        Vb[(size_t)(b * T_ + t0 + ty + j*8) * (HKV_*DH_) + kv*DH_ + d0 + tx];
  __syncthreads();
#pragma unroll
  for (int j = 0; j < 4; ++j)
    VT[((size_t)bk * DH_ + d0 + ty + j*8) * T_ + t0 + tx] = tile[tx][ty + j*8];
}

// ---------------------------------------------------------------------------
// 6) causal flash attention, BQ=128, BKV=64, 256 threads, 1-D grid of 1024.
//
//    Round-2 restructure (post-mortem of r1: occupancy loss beat pipelining):
//      - NO K/V LDS staging: each wave reads the full K/V tile from LDS
//        anyway (16x16B = whole tile), so staging only saved global-side
//        traffic -- but K/V is 16 MB total (L2/L3-resident). Read K and V
//        fragments directly from global. (Common-mistake #7 / m169.)
//      - ZERO __syncthreads in the kv loop: only LDS use is the wave-private
//        P buffer (same-wave ds ordering via lgkmcnt). Waves/blocks slide
//        freely; global-load latency hidden by TLP.
//      - LDS = 18 KB -> occupancy VGPR-limited (>=3 blocks/CU).
//      - XCD-locality decode: 16 (b,kv) K/V groups; xcd = id&7 -> each XCD's
//        64 resident blocks share one 1 MB K/V working set (fits 4 MB L2).
//      - softmax in exp2 domain w/ fused scale; defer-max (T13); setprio (T5).
// ---------------------------------------------------------------------------
__global__ __launch_bounds__(256, 2)
void flash_attn(const bf16_t* __restrict__ Qb, const bf16_t* __restrict__ Kb,
                const bf16_t* __restrict__ VT, bf16_t* __restrict__ Ob) {
  __shared__ __align__(16) bf16_t Pls[128 * 72];   // [q][kv], +8 pad

  const int tid = threadIdx.x, wave = tid >> 6, lane = tid & 63;
  const int quad = lane >> 4, l16 = lane & 15;

  // XCD-locality decode of flat block id (grid = 1024 = 16qt * 32h * 2b)
  const int linear = blockIdx.x;
  const int xcd  = linear & 7;
  const int slot = linear >> 3;                 // 0..127
  const int g    = ((slot >> 6) << 3) + xcd;    // 0..15 = b*8+kv
  const int b    = g >> 3, kv = g & 7;
  const int j    = slot & 63;
  const int qt   = 15 - (j >> 2);               // heavy blocks first
  const int h    = kv * 4 + (j & 3);

  // Q fragments (rope already applied): rows wave*32 + mi*16 + l16
  bf16x8 q[2][4];
#pragma unroll
  for (int mi = 0; mi < 2; ++mi) {
    const bf16_t* base =
        Qb + (size_t)(b*T_ + qt*128 + wave*32 + mi*16 + l16) * DIM_ + h*DH_;
#pragma unroll
    for (int kk = 0; kk < 4; ++kk)
      q[mi][kk] = *(const bf16x8*)(base + kk*32 + quad*8);
  }

  float m_st[2][4], l_st[2][4];
  f32x4 o_acc[2][8] = {};
#pragma unroll
  for (int mi = 0; mi < 2; ++mi)
#pragma unroll
    for (int r = 0; r < 4; ++r) { m_st[mi][r] = -1e30f; l_st[mi][r] = 0.f; }

  const int nkv = 2 * (qt + 1);
  const float S2 = 0.08838834764831845f * 1.4426950408889634f; // sc*log2(e)
  const float THRraw = 8.0f / 0.08838834764831845f;            // defer threshold

  const bf16_t* Kbase = Kb + (size_t)b * T_ * (HKV_*DH_) + kv * DH_;
  const bf16_t* Vbase = VT + (size_t)(b*HKV_ + kv) * DH_ * T_;

  for (int kvt = 0; kvt < nkv; ++kvt) {
    // ---- S = Q K^T : K fragments straight from global (L2-hot) ----
    f32x4 s[2][4] = {};
#pragma unroll
    for (int kk = 0; kk < 4; ++kk) {
      bf16x8 kf[4];
#pragma unroll
      for (int ni = 0; ni < 4; ++ni) {
        int krow = kvt*64 + ni*16 + l16;
        kf[ni] = *(const bf16x8*)(Kbase + (size_t)krow * (HKV_*DH_) + kk*32 + quad*8);
      }
      __builtin_amdgcn_s_setprio(1);
#pragma unroll
      for (int mi = 0; mi < 2; ++mi)
#pragma unroll
        for (int ni = 0; ni < 4; ++ni)
          s[mi][ni] = mfma16(q[mi][kk], kf[ni], s[mi][ni]);
      __builtin_amdgcn_s_setprio(0);
    }

    // ---- causal mask + online softmax (raw-score exp2 domain) ----
    const bool need_mask = (kvt >= 2*qt);
#pragma unroll
    for (int mi = 0; mi < 2; ++mi) {
      float mx[4];
#pragma unroll
      for (int r = 0; r < 4; ++r) {
        int rpos = qt*128 + wave*32 + mi*16 + quad*4 + r;
        float m = -1e30f;
#pragma unroll
        for (int ni = 0; ni < 4; ++ni) {
          float v = s[mi][ni][r];
          if (need_mask) {
            int cpos = kvt*64 + ni*16 + l16;
            if (cpos > rpos) v = -1e30f;
          }
          s[mi][ni][r] = v;
          m = fmaxf(m, v);
        }
#pragma unroll
        for (int off = 1; off < 16; off <<= 1)
          m = fmaxf(m, __shfl_xor(m, off, 64));
        mx[r] = m;
      }
      bool defer = true;
#pragma unroll
      for (int r = 0; r < 4; ++r)
        defer = defer && (mx[r] <= m_st[mi][r] + THRraw);
      if (__all(defer)) {
#pragma unroll
        for (int r = 0; r < 4; ++r) {
          float mn2 = m_st[mi][r] * S2;
          float rs = 0.f;
#pragma unroll
          for (int ni = 0; ni < 4; ++ni) {
            float pv = __builtin_amdgcn_exp2f(fmaf(s[mi][ni][r], S2, -mn2));
            s[mi][ni][r] = pv;
            rs += pv;
          }
#pragma unroll
          for (int off = 1; off < 16; off <<= 1)
            rs += __shfl_xor(rs, off, 64);
          l_st[mi][r] += rs;
        }
      } else {
        float al[4];
#pragma unroll
        for (int r = 0; r < 4; ++r) {
          float mnew = fmaxf(m_st[mi][r], mx[r]);
          al[r] = __builtin_amdgcn_exp2f((m_st[mi][r] - mnew) * S2);
          m_st[mi][r] = mnew;
          float mn2 = mnew * S2;
          float rs = 0.f;
#pragma unroll
          for (int ni = 0; ni < 4; ++ni) {
            float pv = __builtin_amdgcn_exp2f(fmaf(s[mi][ni][r], S2, -mn2));
            s[mi][ni][r] = pv;
            rs += pv;
          }
#pragma unroll
          for (int off = 1; off < 16; off <<= 1)
            rs += __shfl_xor(rs, off, 64);
          l_st[mi][r] = l_st[mi][r] * al[r] + rs;
        }
#pragma unroll
        for (int ni = 0; ni < 8; ++ni)
#pragma unroll
          for (int r = 0; r < 4; ++r) o_acc[mi][ni][r] *= al[r];
      }
      // P -> LDS (wave-private rows; same-wave ds ordering, no barrier)
#pragma unroll
      for (int ni = 0; ni < 4; ++ni)
#pragma unroll
        for (int r = 0; r < 4; ++r) {
          int prow = wave*32 + mi*16 + quad*4 + r;
          Pls[prow*72 + ni*16 + l16] = (bf16_t)s[mi][ni][r];
        }
    }

    // ---- O += P V : P from LDS, V fragments straight from global ----
    bf16x8 pf[2][2];
#pragma unroll
    for (int kk = 0; kk < 2; ++kk)
#pragma unroll
      for (int mi = 0; mi < 2; ++mi)
        pf[kk][mi] = *(const bf16x8*)&Pls[(wave*32 + mi*16 + l16)*72 + kk*32 + quad*8];
#pragma unroll
    for (int ni = 0; ni < 8; ++ni) {
      int drow = ni*16 + l16;
      const bf16_t* vb = Vbase + (size_t)drow * T_ + kvt*64;
      bf16x8 va = *(const bf16x8*)(vb + quad*8);
      bf16x8 vc = *(const bf16x8*)(vb + 32 + quad*8);
      __builtin_amdgcn_s_setprio(1);
      o_acc[0][ni] = mfma16(pf[0][0], va, o_acc[0][ni]);
      o_acc[1][ni] = mfma16(pf[0][1], va, o_acc[1][ni]);
      o_acc[0][ni] = mfma16(pf[1][0], vc, o_acc[0][ni]);
      o_acc[1][ni] = mfma16(pf[1][1], vc, o_acc[1][ni]);
      __builtin_amdgcn_s_setprio(0);
    }
  }

  // epilogue: normalize and store bf16
#pragma unroll
  for (int mi = 0; mi < 2; ++mi) {
    float inv[4];
#pragma unroll
    for (int r = 0; r < 4; ++r) inv[r] = 1.f / l_st[mi][r];
#pragma unroll
    for (int ni = 0; ni < 8; ++ni)
#pragma unroll
      for (int r = 0; r < 4; ++r) {
        size_t row = (size_t)(b*T_ + qt*128 + wave*32 + mi*16 + quad*4 + r);
        int col = h*DH_ + ni*16 + l16;
        Ob[row * DIM_ + col] = (bf16_t)(o_acc[mi][ni][r] * inv[r]);
      }
  }
}

// ---------------------------------------------------------------------------
// launch
// ---------------------------------------------------------------------------
extern "C" void kernel_launch(void* const* d_in, const int* in_sizes, int n_in,
                              void* d_out, int out_size, void* d_ws, size_t ws_size,
                              hipStream_t stream) {
  const float* X  = (const float*)d_in[0];
  const float* Wq = (const float*)d_in[1];
  const float* Wk = (const float*)d_in[2];
  const float* Wv = (const float*)d_in[3];
  const float* Wo = (const float*)d_in[4];
  float* out = (float*)d_out;

  // workspace layout (bytes); total ~176.2 MB
  char* ws = (char*)d_ws;
  const size_t SZ_X  = (size_t)MROWS * DIM_ * 2;   // 33.55 MB
  const size_t SZ_WQ = (size_t)DIM_ * DIM_ * 2;    // 33.55 MB
  const size_t SZ_WK = (size_t)DIM_ * 1024 * 2;    // 8.39 MB
  bf16_t* Xb  = (bf16_t*)(ws);                       // X bf16; reused as Ob
  bf16_t* WqT = (bf16_t*)(ws + SZ_X);
  bf16_t* WkT = (bf16_t*)(ws + SZ_X + SZ_WQ);
  bf16_t* WvT = (bf16_t*)(ws + SZ_X + SZ_WQ + SZ_WK);
  bf16_t* WoT = (bf16_t*)(ws + SZ_X + SZ_WQ + 2*SZ_WK);
  bf16_t* Qb  = (bf16_t*)(ws + SZ_X + 2*SZ_WQ + 2*SZ_WK);
  bf16_t* Kb  = (bf16_t*)(ws + 2*SZ_X + 2*SZ_WQ + 2*SZ_WK);
  bf16_t* Vb  = (bf16_t*)(ws + 2*SZ_X + 2*SZ_WQ + 3*SZ_WK);
  bf16_t* VT  = (bf16_t*)(ws + 2*SZ_X + 2*SZ_WQ + 4*SZ_WK);
  bf16_t* Ob  = Xb;  // X dead after QKV GEMMs

  // 1) casts / transposes
  {
    int n4 = MROWS * DIM_ / 4;
    cast_f32_bf16<<<(n4 + 255)/256, 256, 0, stream>>>(X, Xb, n4);
  }
  transpose_cast<<<dim3(DIM_/32, DIM_/32), dim3(32,8), 0, stream>>>(Wq, WqT, DIM_, DIM_);
  transpose_cast<<<dim3(1024/32, DIM_/32), dim3(32,8), 0, stream>>>(Wk, WkT, DIM_, 1024);
  transpose_cast<<<dim3(1024/32, DIM_/32), dim3(32,8), 0, stream>>>(Wv, WvT, DIM_, 1024);
  transpose_cast<<<dim3(DIM_/32, DIM_/32), dim3(32,8), 0, stream>>>(Wo, WoT, DIM_, DIM_);

  // 2) QKV projections
  gemm_bt<0><<<dim3(DIM_/128, MROWS/128), 256, 0, stream>>>(Xb, WqT, Qb, MROWS, DIM_, DIM_);
  gemm_bt<0><<<dim3(1024/128, MROWS/128), 256, 0, stream>>>(Xb, WkT, Kb, MROWS, 1024, DIM_);
  gemm_bt<0><<<dim3(1024/128, MROWS/128), 256, 0, stream>>>(Xb, WvT, Vb, MROWS, 1024, DIM_);

  // 3) RoPE (in place)
  {
    int totq = B_ * T_ * H_ * 64;
    rope_kernel<<<(totq + 255)/256, 256, 0, stream>>>(Qb, H_, totq);
    int totk = B_ * T_ * HKV_ * 64;
    rope_kernel<<<(totk + 255)/256, 256, 0, stream>>>(Kb, HKV_, totk);
  }

  // 4) V transpose
  v_transpose<<<dim3(T_/32, DH_/32, B_*HKV_), dim3(32,8), 0, stream>>>(Vb, VT);

  // 5) flash attention (1-D grid, XCD-locality decode inside)
  flash_attn<<<dim3((T_/128) * H_ * B_), 256, 0, stream>>>(Qb, Kb, VT, Ob);

  // 6) output projection -> fp32 d_out
  gemm_bt<1><<<dim3(DIM_/128, MROWS/128), 256, 0, stream>>>(Ob, WoT, out, MROWS, DIM_, DIM_);
}

// Round 3
// 901.316 us; speedup vs baseline: 1.1922x; 1.0977x over previous
//
#include <hip/hip_runtime.h>
#include <hip/hip_bf16.h>
#include <cstdint>
#include <cstddef>

// Problem constants
#define B_   2
#define T_   2048
#define DIM_ 4096
#define H_   32
#define HKV_ 8
#define DH_  128
#define MROWS (B_*T_)    // 4096
#define QKV_LD 6144      // fused QKV row stride (4096 Q + 1024 K + 1024 V)

typedef __bf16 bf16_t;
typedef bf16_t bf16x8 __attribute__((ext_vector_type(8)));
typedef bf16_t bf16x4 __attribute__((ext_vector_type(4)));
typedef float  f32x4  __attribute__((ext_vector_type(4)));

typedef __attribute__((address_space(1))) void gvoid_t;
typedef __attribute__((address_space(3))) void lvoid_t;

__device__ __forceinline__ void gld_lds16(const void* g, void* l) {
  __builtin_amdgcn_global_load_lds((gvoid_t*)g, (lvoid_t*)l, 16, 0, 0);
}

__device__ __forceinline__ f32x4 mfma16(bf16x8 a, bf16x8 b, f32x4 c) {
  return __builtin_amdgcn_mfma_f32_16x16x32_bf16(a, b, c, 0, 0, 0);
}

// ---------------------------------------------------------------------------
// 1) elementwise cast fp32 -> bf16 (X)
// ---------------------------------------------------------------------------
__global__ void cast_f32_bf16(const float* __restrict__ in,
                              bf16_t* __restrict__ out, int n4) {
  int i = blockIdx.x * blockDim.x + threadIdx.x;
  if (i < n4) {
    float4 v = ((const float4*)in)[i];
    bf16x4 o;
    o[0] = (bf16_t)v.x; o[1] = (bf16_t)v.y; o[2] = (bf16_t)v.z; o[3] = (bf16_t)v.w;
    ((bf16x4*)out)[i] = o;
  }
}

// ---------------------------------------------------------------------------
// 2) transpose + cast: in fp32 [K][N] -> out bf16 [N][K]
// ---------------------------------------------------------------------------
__global__ void transpose_cast(const float* __restrict__ in,
                               bf16_t* __restrict__ out, int K, int N) {
  __shared__ float tile[32][33];
  int n0 = blockIdx.x * 32, k0 = blockIdx.y * 32;
  int tx = threadIdx.x, ty = threadIdx.y;
#pragma unroll
  for (int j = 0; j < 4; ++j)
    tile[ty + j*8][tx] = in[(size_t)(k0 + ty + j*8) * N + n0 + tx];
  __syncthreads();
#pragma unroll
  for (int j = 0; j < 4; ++j)
    out[(size_t)(n0 + ty + j*8) * K + k0 + tx] = (bf16_t)tile[tx][ty + j*8];
}

// ---------------------------------------------------------------------------
// 3) bf16 MFMA GEMM, m97 structure: C[M][N] = A[M][K] * BT[N][K]^T
// ---------------------------------------------------------------------------
template <int OUT_F32>
__global__ __launch_bounds__(256, 2)
void gemm_bt(const bf16_t* __restrict__ A, const bf16_t* __restrict__ BT,
             void* __restrict__ C, int M, int N, int K) {
  __shared__ __align__(16) bf16_t Als[128 * 32];
  __shared__ __align__(16) bf16_t Bls[128 * 32];
  const int tid  = threadIdx.x;
  const int wave = tid >> 6, lane = tid & 63;
  const int quad = lane >> 4, l16 = lane & 15;
  const int wm = wave >> 1, wn = wave & 1;
  const int m0 = blockIdx.y * 128, n0 = blockIdx.x * 128;

  f32x4 acc[4][4] = {};

  const int srow = lane >> 2;
  const int scol = (lane & 3) * 8;

  for (int k0 = 0; k0 < K; k0 += 32) {
#pragma unroll
    for (int c = 0; c < 2; ++c) {
      int ch = wave * 2 + c;
      gld_lds16(A + (size_t)(m0 + ch*16 + srow) * K + k0 + scol,
                &Als[ch*512 + srow*32 + scol]);
    }
#pragma unroll
    for (int c = 0; c < 2; ++c) {
      int ch = wave * 2 + c;
      gld_lds16(BT + (size_t)(n0 + ch*16 + srow) * K + k0 + scol,
                &Bls[ch*512 + srow*32 + scol]);
    }
    __syncthreads();

    bf16x8 af[4], bfr[4];
#pragma unroll
    for (int mi = 0; mi < 4; ++mi)
      af[mi] = *(const bf16x8*)&Als[(wm*64 + mi*16 + l16)*32 + quad*8];
#pragma unroll
    for (int ni = 0; ni < 4; ++ni)
      bfr[ni] = *(const bf16x8*)&Bls[(wn*64 + ni*16 + l16)*32 + quad*8];
#pragma unroll
    for (int mi = 0; mi < 4; ++mi)
#pragma unroll
      for (int ni = 0; ni < 4; ++ni)
        acc[mi][ni] = mfma16(af[mi], bfr[ni], acc[mi][ni]);
    __syncthreads();
  }

#pragma unroll
  for (int mi = 0; mi < 4; ++mi)
#pragma unroll
    for (int ni = 0; ni < 4; ++ni)
#pragma unroll
      for (int r = 0; r < 4; ++r) {
        int row = m0 + wm*64 + mi*16 + quad*4 + r;
        int col = n0 + wn*64 + ni*16 + l16;
        if (OUT_F32)
          ((float*)C)[(size_t)row * N + col] = acc[mi][ni][r];
        else
          ((bf16_t*)C)[(size_t)row * N + col] = (bf16_t)acc[mi][ni][r];
      }
}

// ---------------------------------------------------------------------------
// 4) in-place RoPE on bf16 rows of stride ld; head layout [Hn][128] at col h*128
// ---------------------------------------------------------------------------
__global__ void rope_kernel(bf16_t* __restrict__ X, int Hn, int ld, int total) {
  int i = blockIdx.x * blockDim.x + threadIdx.x;
  if (i >= total) return;
  int d   = i & 63;
  int rem = i >> 6;
  int h   = rem % Hn; rem /= Hn;
  int t   = rem % T_;
  int b   = rem / T_;
  size_t base = (size_t)(b * T_ + t) * ld + h * DH_;
  float x1 = (float)X[base + d];
  float x2 = (float)X[base + 64 + d];
  float inv_freq = expf(-(float)d * 0.14391156758f);
  float ang = (float)t * inv_freq;
  float s, c;
  sincosf(ang, &s, &c);
  X[base + d]      = (bf16_t)(x1 * c - x2 * s);
  X[base + 64 + d] = (bf16_t)(x1 * s + x2 * c);
}

// ---------------------------------------------------------------------------
// 5) V transpose: V rows (stride ld) [b][t][kv*128+d] -> VT [b][kv][128][T]
// ---------------------------------------------------------------------------
__global__ void v_transpose(const bf16_t* __restrict__ Vb,
                            bf16_t* __restrict__ VT, int ld) {
  __shared__ bf16_t tile[32][33];
  int t0 = blockIdx.x * 32;
  int d0 = blockIdx.y * 32;
  int bk = blockIdx.z;
  int b = bk >> 3, kv = bk & 7;
  int tx = threadIdx.x, ty = threadIdx.y;
#pragma unroll
  for (int j = 0; j < 4; ++j)
    tile[ty + j*8][tx] =
        Vb[(size_t)(b * T_ + t0 + ty + j*8) * ld + kv*DH_ + d0 + tx];
  __syncthreads();
#pragma unroll
  for (int j = 0; j < 4; ++j)
    VT[((size_t)bk * DH_ + d0 + ty + j*8) * T_ + t0 + tx] = tile[tx][ty + j*8];
}

// ---------------------------------------------------------------------------
// 6) causal flash attention, BQ=128, BKV=64, 256 threads, 1-D grid of 1024.
//    Round-3 softmax restructure (r2 post-mortem: shuffle chains dominate):
//      - l via MFMA: l_acc = mfma(P-frag, ones) accumulated like o_acc;
//        sum butterfly (32 shfl/iter) deleted.
//      - vote-only max: defer vote needs only __all(in-lane max <= m+THR);
//        full butterfly max only on rare rescale path. (32 shfl/iter deleted.)
//      - common path: masked in-lane fmax, 1 wave vote, 32 exp2, P write.
//    Q/K read from fused QKV buffer (row stride 6144); V via VT.
// ---------------------------------------------------------------------------
__global__ __launch_bounds__(256, 2)
void flash_attn(const bf16_t* __restrict__ QKV, const bf16_t* __restrict__ VT,
                bf16_t* __restrict__ Ob) {
  __shared__ __align__(16) bf16_t Pls[128 * 72];   // [q][kv], +8 pad

  const int tid = threadIdx.x, wave = tid >> 6, lane = tid & 63;
  const int quad = lane >> 4, l16 = lane & 15;

  // XCD-locality decode of flat block id (grid = 1024 = 16qt * 32h * 2b)
  const int linear = blockIdx.x;
  const int xcd  = linear & 7;
  const int slot = linear >> 3;                 // 0..127
  const int g    = ((slot >> 6) << 3) + xcd;    // 0..15 = b*8+kv
  const int b    = g >> 3, kv = g & 7;
  const int j    = slot & 63;
  const int qt   = 15 - (j >> 2);               // heavy blocks first
  const int h    = kv * 4 + (j & 3);

  // Q fragments (rope already applied): rows wave*32 + mi*16 + l16
  bf16x8 q[2][4];
#pragma unroll
  for (int mi = 0; mi < 2; ++mi) {
    const bf16_t* base =
        QKV + (size_t)(b*T_ + qt*128 + wave*32 + mi*16 + l16) * QKV_LD + h*DH_;
#pragma unroll
    for (int kk = 0; kk < 4; ++kk)
      q[mi][kk] = *(const bf16x8*)(base + kk*32 + quad*8);
  }

  float m_st[2][4];
  f32x4 o_acc[2][8] = {};
  f32x4 l_acc[2] = {};
#pragma unroll
  for (int mi = 0; mi < 2; ++mi)
#pragma unroll
    for (int r = 0; r < 4; ++r) m_st[mi][r] = -1e30f;

  const int nkv = 2 * (qt + 1);
  const float S2 = 0.08838834764831845f * 1.4426950408889634f; // sc*log2(e)
  const float THRraw = 8.0f / 0.08838834764831845f;            // defer threshold

  const bf16_t* Kbase = QKV + DIM_ + (size_t)b * T_ * QKV_LD + kv * DH_;
  const bf16_t* Vbase = VT + (size_t)(b*HKV_ + kv) * DH_ * T_;

  bf16x8 vones;
#pragma unroll
  for (int i = 0; i < 8; ++i) vones[i] = (bf16_t)1.0f;

  for (int kvt = 0; kvt < nkv; ++kvt) {
    // ---- S = Q K^T : K fragments straight from global (L2-hot) ----
    f32x4 s[2][4] = {};
#pragma unroll
    for (int kk = 0; kk < 4; ++kk) {
      bf16x8 kf[4];
#pragma unroll
      for (int ni = 0; ni < 4; ++ni) {
        int krow = kvt*64 + ni*16 + l16;
        kf[ni] = *(const bf16x8*)(Kbase + (size_t)krow * QKV_LD + kk*32 + quad*8);
      }
      __builtin_amdgcn_s_setprio(1);
#pragma unroll
      for (int mi = 0; mi < 2; ++mi)
#pragma unroll
        for (int ni = 0; ni < 4; ++ni)
          s[mi][ni] = mfma16(q[mi][kk], kf[ni], s[mi][ni]);
      __builtin_amdgcn_s_setprio(0);
    }

    // ---- causal mask + online softmax (vote-only max; l via MFMA) ----
    const bool need_mask = (kvt >= 2*qt);
#pragma unroll
    for (int mi = 0; mi < 2; ++mi) {
      float lmax[4];
#pragma unroll
      for (int r = 0; r < 4; ++r) {
        int rpos = qt*128 + wave*32 + mi*16 + quad*4 + r;
        float m = -1e30f;
#pragma unroll
        for (int ni = 0; ni < 4; ++ni) {
          float v = s[mi][ni][r];
          if (need_mask) {
            int cpos = kvt*64 + ni*16 + l16;
            if (cpos > rpos) v = -1e30f;
          }
          s[mi][ni][r] = v;
          m = fmaxf(m, v);
        }
        lmax[r] = m;
      }
      bool defer = (lmax[0] <= m_st[mi][0] + THRraw) &
                   (lmax[1] <= m_st[mi][1] + THRraw) &
                   (lmax[2] <= m_st[mi][2] + THRraw) &
                   (lmax[3] <= m_st[mi][3] + THRraw);
      if (!__all(defer)) {
        float al[4];
#pragma unroll
        for (int r = 0; r < 4; ++r) {
          float m = lmax[r];
#pragma unroll
          for (int off = 1; off < 16; off <<= 1)
            m = fmaxf(m, __shfl_xor(m, off, 64));
          float mnew = fmaxf(m_st[mi][r], m);
          al[r] = __builtin_amdgcn_exp2f((m_st[mi][r] - mnew) * S2);
          m_st[mi][r] = mnew;
        }
#pragma unroll
        for (int ni = 0; ni < 8; ++ni)
#pragma unroll
          for (int r = 0; r < 4; ++r) o_acc[mi][ni][r] *= al[r];
#pragma unroll
        for (int r = 0; r < 4; ++r) l_acc[mi][r] *= al[r];
      }
      // exp2 + P write (common path; wave-private rows, no barrier)
#pragma unroll
      for (int r = 0; r < 4; ++r) {
        float mn2 = m_st[mi][r] * S2;
        int prow = wave*32 + mi*16 + quad*4 + r;
#pragma unroll
        for (int ni = 0; ni < 4; ++ni) {
          float pv = __builtin_amdgcn_exp2f(fmaf(s[mi][ni][r], S2, -mn2));
          Pls[prow*72 + ni*16 + l16] = (bf16_t)pv;
        }
      }
    }

    // ---- O += P V ; l += P 1 (MFMA rowsum) ----
    bf16x8 pf[2][2];
#pragma unroll
    for (int kk = 0; kk < 2; ++kk)
#pragma unroll
      for (int mi = 0; mi < 2; ++mi)
        pf[kk][mi] = *(const bf16x8*)&Pls[(wave*32 + mi*16 + l16)*72 + kk*32 + quad*8];

    __builtin_amdgcn_s_setprio(1);
    l_acc[0] = mfma16(pf[0][0], vones, l_acc[0]);
    l_acc[1] = mfma16(pf[0][1], vones, l_acc[1]);
    l_acc[0] = mfma16(pf[1][0], vones, l_acc[0]);
    l_acc[1] = mfma16(pf[1][1], vones, l_acc[1]);
    __builtin_amdgcn_s_setprio(0);

#pragma unroll
    for (int ni = 0; ni < 8; ++ni) {
      int drow = ni*16 + l16;
      const bf16_t* vb = Vbase + (size_t)drow * T_ + kvt*64;
      bf16x8 va = *(const bf16x8*)(vb + quad*8);
      bf16x8 vc = *(const bf16x8*)(vb + 32 + quad*8);
      __builtin_amdgcn_s_setprio(1);
      o_acc[0][ni] = mfma16(pf[0][0], va, o_acc[0][ni]);
      o_acc[1][ni] = mfma16(pf[0][1], va, o_acc[1][ni]);
      o_acc[0][ni] = mfma16(pf[1][0], vc, o_acc[0][ni]);
      o_acc[1][ni] = mfma16(pf[1][1], vc, o_acc[1][ni]);
      __builtin_amdgcn_s_setprio(0);
    }
  }

  // epilogue: normalize (l from MFMA rowsum) and store bf16
#pragma unroll
  for (int mi = 0; mi < 2; ++mi) {
    float inv[4];
#pragma unroll
    for (int r = 0; r < 4; ++r) inv[r] = 1.f / l_acc[mi][r];
#pragma unroll
    for (int ni = 0; ni < 8; ++ni)
#pragma unroll
      for (int r = 0; r < 4; ++r) {
        size_t row = (size_t)(b*T_ + qt*128 + wave*32 + mi*16 + quad*4 + r);
        int col = h*DH_ + ni*16 + l16;
        Ob[row * DIM_ + col] = (bf16_t)(o_acc[mi][ni][r] * inv[r]);
      }
  }
}

// ---------------------------------------------------------------------------
// launch
// ---------------------------------------------------------------------------
extern "C" void kernel_launch(void* const* d_in, const int* in_sizes, int n_in,
                              void* d_out, int out_size, void* d_ws, size_t ws_size,
                              hipStream_t stream) {
  const float* X  = (const float*)d_in[0];
  const float* Wq = (const float*)d_in[1];
  const float* Wk = (const float*)d_in[2];
  const float* Wv = (const float*)d_in[3];
  const float* Wo = (const float*)d_in[4];
  float* out = (float*)d_out;

  // workspace layout (bytes); total ~176.2 MB (same as before)
  char* ws = (char*)d_ws;
  const size_t SZ_X   = (size_t)MROWS * DIM_ * 2;     // 33.55 MB
  const size_t SZ_WQ  = (size_t)DIM_ * DIM_ * 2;      // 33.55 MB
  const size_t SZ_WK  = (size_t)DIM_ * 1024 * 2;      // 8.39 MB
  const size_t SZ_QKV = (size_t)MROWS * QKV_LD * 2;   // 50.33 MB
  bf16_t* Xb  = (bf16_t*)(ws);                        // X bf16; reused as Ob
  bf16_t* WqT = (bf16_t*)(ws + SZ_X);                 // [4096][4096]
  // WkT, WvT immediately follow WqT -> fused BT [6144][4096]
  bf16_t* WkT = (bf16_t*)(ws + SZ_X + SZ_WQ);         // [1024][4096]
  bf16_t* WvT = (bf16_t*)(ws + SZ_X + SZ_WQ + SZ_WK); // [1024][4096]
  bf16_t* WoT = (bf16_t*)(ws + SZ_X + SZ_WQ + 2*SZ_WK);
  bf16_t* QKV = (bf16_t*)(ws + SZ_X + 2*SZ_WQ + 2*SZ_WK);  // [4096][6144]
  bf16_t* VT  = (bf16_t*)(ws + SZ_X + 2*SZ_WQ + 2*SZ_WK + SZ_QKV);
  bf16_t* Ob  = Xb;  // X dead after QKV GEMM

  // 1) casts / transposes
  {
    int n4 = MROWS * DIM_ / 4;
    cast_f32_bf16<<<(n4 + 255)/256, 256, 0, stream>>>(X, Xb, n4);
  }
  transpose_cast<<<dim3(DIM_/32, DIM_/32), dim3(32,8), 0, stream>>>(Wq, WqT, DIM_, DIM_);
  transpose_cast<<<dim3(1024/32, DIM_/32), dim3(32,8), 0, stream>>>(Wk, WkT, DIM_, 1024);
  transpose_cast<<<dim3(1024/32, DIM_/32), dim3(32,8), 0, stream>>>(Wv, WvT, DIM_, 1024);
  transpose_cast<<<dim3(DIM_/32, DIM_/32), dim3(32,8), 0, stream>>>(Wo, WoT, DIM_, DIM_);

  // 2) fused QKV projection: C[4096][6144] = Xb * [Wq|Wk|Wv]
  gemm_bt<0><<<dim3(QKV_LD/128, MROWS/128), 256, 0, stream>>>(Xb, WqT, QKV, MROWS, QKV_LD, DIM_);

  // 3) RoPE (in place, inside fused buffer)
  {
    int totq = B_ * T_ * H_ * 64;
    rope_kernel<<<(totq + 255)/256, 256, 0, stream>>>(QKV, H_, QKV_LD, totq);
    int totk = B_ * T_ * HKV_ * 64;
    rope_kernel<<<(totk + 255)/256, 256, 0, stream>>>(QKV + DIM_, HKV_, QKV_LD, totk);
  }

  // 4) V transpose (V columns live at QKV + 5120)
  v_transpose<<<dim3(T_/32, DH_/32, B_*HKV_), dim3(32,8), 0, stream>>>(QKV + DIM_ + 1024, VT, QKV_LD);

  // 5) flash attention (1-D grid, XCD-locality decode inside)
  flash_attn<<<dim3((T_/128) * H_ * B_), 256, 0, stream>>>(QKV, VT, Ob);

  // 6) output projection -> fp32 d_out
  gemm_bt<1><<<dim3(DIM_/128, MROWS/128), 256, 0, stream>>>(Ob, WoT, out, MROWS, DIM_, DIM_);
}